// Round 17
// baseline (150.325 us; speedup 1.0000x reference)
//
#include <hip/hip_runtime.h>

// Problem constants
#define C_DIM   256
#define K_CODES 1024
#define HW      1024
#define NPOS    32768            // B*H*W
#define ZQ_ELEMS 8388608         // B*C*H*W

typedef float  f32x4  __attribute__((ext_vector_type(4)));
typedef __bf16 bf16x8 __attribute__((ext_vector_type(8)));

// workspace byte offsets
#define OFF_EF    0                      // 1024 f32
#define OFF_BB    4096                   // 512 KB packed bf16 codebook image
#define OFF_IDX   (4096 + 524288)        // 32768 int
#define OFF_LIST  (OFF_IDX + 131072)     // 32768 int
#define OFF_COUNT (OFF_LIST + 131072)    // int
#define OFF_LSUM  (OFF_COUNT + 8)        // double
#define OFF_ET    790656                 // 1 MB f32 transposed codebook [c][k]
#define OFF_SLOT  1839232                // 256 KB u64 per-row argmin slots
#define OFF_PD    2101376                // 2048 doubles: per-block loss partials
#define OFF_ZN    2117760                // 32768 f32: per-flagged-row ||z||^2
#define OFF_ZC    2248832                // compact z rows for flagged list (cap'd by ws)

// flag margin (validated rounds 11-16 at 4e-4)
#define TAU2 4e-4f

static __device__ __forceinline__ uint32_t umin32(uint32_t a, uint32_t b) { return a < b ? a : b; }
static __device__ __forceinline__ uint32_t umax32(uint32_t a, uint32_t b) { return a > b ? a : b; }

// ---------------------------------------------------------------------------
// k1: faithful fp32 ||e_k||^2 (numpy pairwise emulation, validated round 2)
//     + pack codebook to chunk-linear swizzled bf16 image Bb + init scalars.
// ---------------------------------------------------------------------------
__global__ __launch_bounds__(256) void k1_prep(const float* __restrict__ emb,
                                               float* __restrict__ Ef,
                                               char* __restrict__ Bb,
                                               int* __restrict__ count,
                                               double* __restrict__ lsum) {
    const int k = blockIdx.x * 256 + threadIdx.x;
    if (k == 0) { *count = 0; *lsum = 0.0; }
    const float* a = emb + (size_t)k * C_DIM;

    float blk[2];
#pragma unroll
    for (int h = 0; h < 2; ++h) {
        const float* p = a + h * 128;
        float4 v0 = *reinterpret_cast<const float4*>(p);
        float4 v1 = *reinterpret_cast<const float4*>(p + 4);
        float r[8];
        r[0] = __fmul_rn(v0.x, v0.x); r[1] = __fmul_rn(v0.y, v0.y);
        r[2] = __fmul_rn(v0.z, v0.z); r[3] = __fmul_rn(v0.w, v0.w);
        r[4] = __fmul_rn(v1.x, v1.x); r[5] = __fmul_rn(v1.y, v1.y);
        r[6] = __fmul_rn(v1.z, v1.z); r[7] = __fmul_rn(v1.w, v1.w);
        for (int i = 8; i < 128; i += 8) {
            float4 w0 = *reinterpret_cast<const float4*>(p + i);
            float4 w1 = *reinterpret_cast<const float4*>(p + i + 4);
            r[0] = __fadd_rn(r[0], __fmul_rn(w0.x, w0.x));
            r[1] = __fadd_rn(r[1], __fmul_rn(w0.y, w0.y));
            r[2] = __fadd_rn(r[2], __fmul_rn(w0.z, w0.z));
            r[3] = __fadd_rn(r[3], __fmul_rn(w0.w, w0.w));
            r[4] = __fadd_rn(r[4], __fmul_rn(w1.x, w1.x));
            r[5] = __fadd_rn(r[5], __fmul_rn(w1.y, w1.y));
            r[6] = __fadd_rn(r[6], __fmul_rn(w1.z, w1.z));
            r[7] = __fadd_rn(r[7], __fmul_rn(w1.w, w1.w));
        }
        blk[h] = __fadd_rn(__fadd_rn(__fadd_rn(r[0], r[1]), __fadd_rn(r[2], r[3])),
                           __fadd_rn(__fadd_rn(r[4], r[5]), __fadd_rn(r[6], r[7])));
    }
    Ef[k] = __fadd_rn(blk[0], blk[1]);

    const int r = k & 63, chunk = k >> 6;
    const int xr = ((r ^ (r >> 2)) & 3) << 4;
    char* base = Bb + (size_t)chunk * 32768 + r * 64;
#pragma unroll
    for (int s = 0; s < 8; ++s) {
        const float* ep = a + s * 32;
        char* sb = base + s * 4096;
#pragma unroll
        for (int g = 0; g < 4; ++g) {
            union { __bf16 h[8]; uint4 v; } pk;
#pragma unroll
            for (int j = 0; j < 8; ++j) pk.h[j] = (__bf16)ep[g * 8 + j];
            *reinterpret_cast<uint4*>(sb + ((g * 16) ^ xr)) = pk.v;
        }
    }
}

// ---------------------------------------------------------------------------
// k1t: codebook transpose (validated round 8) + init u64 argmin slots.
// ---------------------------------------------------------------------------
__global__ __launch_bounds__(256) void k1t(const float* __restrict__ emb,
                                           float* __restrict__ embT,
                                           unsigned long long* __restrict__ slots) {
    const int tid = blockIdx.x * 256 + threadIdx.x;
    slots[tid * 2]     = ~0ull;
    slots[tid * 2 + 1] = ~0ull;

    __shared__ float tile[64][65];
    const int l = threadIdx.x & 63, w = threadIdx.x >> 6;
    const int k0 = (blockIdx.x & 15) * 64;
    const int c0 = (blockIdx.x >> 4) * 64;
#pragma unroll
    for (int i = 0; i < 16; ++i)
        tile[l][w * 16 + i] = emb[(size_t)(k0 + w * 16 + i) * C_DIM + c0 + l];
    __syncthreads();
#pragma unroll
    for (int i = 0; i < 16; ++i)
        embT[(size_t)(c0 + w * 16 + i) * K_CODES + k0 + l] = tile[w * 16 + i][l];
}

// ---------------------------------------------------------------------------
// k2 v4: barrier-free MFMA scoring GEMM with register double-buffered B
// prefetch (load chunk g+1 while chunk g computes). Numerics/epilogue
// byte-identical to the validated rounds 9/11-16 version.
// ---------------------------------------------------------------------------
__global__ __launch_bounds__(512, 2) void k2_gemm(const float* __restrict__ z,
                                                  const char* __restrict__ Bb,
                                                  const float* __restrict__ Ef,
                                                  int* __restrict__ idxf,
                                                  int* __restrict__ list,
                                                  int* __restrict__ count) {
    __shared__ char As[65536];             // A image; reused for final merge

    const int t    = threadIdx.x;
    const int bidx = blockIdx.x;
    const int lane = t & 63;
    const int l15  = lane & 15, kg = lane >> 4;
    const int wid  = t >> 6;
    const int wM   = wid >> 2, wN = wid & 3;   // 2M x 4N waves

    const float* zt = z + (size_t)(bidx >> 3) * (C_DIM * HW) + (bidx & 7) * 128;
#pragma unroll
    for (int p = 0; p < 8; ++p) {
        const int pi  = p * 512 + t;
        const int c2  = pi >> 5;
        const int hwg = pi & 31;
        const float* p0 = zt + (size_t)(2 * c2) * HW + hwg * 4;
        const float4 f0 = *reinterpret_cast<const float4*>(p0);
        const float4 f1 = *reinterpret_cast<const float4*>(p0 + HW);
        const float a0v[4] = {f0.x, f0.y, f0.z, f0.w};
        const float a1v[4] = {f1.x, f1.y, f1.z, f1.w};
#pragma unroll
        for (int i = 0; i < 4; ++i) {
            const int hw = hwg * 4 + i;
            const int xr = ((hw ^ (hw >> 2)) & 7) << 4;
            const int koff = (c2 * 4) ^ xr;
            union { __bf16 h[2]; unsigned int u; } ph;
            ph.h[0] = (__bf16)a0v[i];
            ph.h[1] = (__bf16)a1v[i];
            *reinterpret_cast<unsigned int*>(As + hw * 512 + koff) = ph.u;
        }
    }
    __syncthreads();

    bf16x8 af[4][8];
#pragma unroll
    for (int mi = 0; mi < 4; ++mi) {
        const int row = wM * 64 + mi * 16 + l15;
        const int axr = ((row ^ (row >> 2)) & 7) << 4;
#pragma unroll
        for (int ks = 0; ks < 8; ++ks)
            af[mi][ks] = *reinterpret_cast<const bf16x8*>(
                As + row * 512 + ((ks * 64 + kg * 16) ^ axr));
    }

    const int rB  = wN * 16 + l15;               // code within chunk
    const int swz = ((rB ^ (rB >> 2)) & 3) << 4;
    const size_t voff = (size_t)rB * 64 + ((kg * 16) ^ swz);

    uint32_t b0[16], b1[16];
#pragma unroll
    for (int s = 0; s < 16; ++s) { b0[s] = 0xFFFFFFFFu; b1[s] = 0xFFFFFFFFu; }

    auto load_chunk = [&](int g, uint4 (&ld)[8]) {
        const char* bgp = Bb + (size_t)g * 32768 + voff;
#pragma unroll
        for (int ks = 0; ks < 8; ++ks)
            ld[ks] = *reinterpret_cast<const uint4*>(bgp + ks * 4096);
    };

    auto do_chunk = [&](int g, uint4 (&ld)[8]) {
        const float efb = Ef[g * 64 + rB] + 0.5f;
        f32x4 acc[4];
#pragma unroll
        for (int mi = 0; mi < 4; ++mi) acc[mi] = f32x4{0.f, 0.f, 0.f, 0.f};
#pragma unroll
        for (int ks = 0; ks < 8; ++ks) {
            union { uint4 u; bf16x8 b; } cv;
            cv.u = ld[ks];
#pragma unroll
            for (int mi = 0; mi < 4; ++mi)
                acc[mi] = __builtin_amdgcn_mfma_f32_16x16x32_bf16(
                    af[mi][ks], cv.b, acc[mi], 0, 0, 0);
        }
        const uint32_t code = (uint32_t)(g * 64 + rB);
#pragma unroll
        for (int mi = 0; mi < 4; ++mi)
#pragma unroll
            for (int rr = 0; rr < 4; ++rr) {
                const float sp = __fmaf_rn(acc[mi][rr], -2.0f, efb);
                const uint32_t key = (__float_as_uint(sp) & 0xFFFFFC00u) | code;
                const int slot = mi * 4 + rr;
                const uint32_t lo = umin32(b0[slot], key);
                const uint32_t hi = umax32(b0[slot], key);
                b0[slot] = lo;
                b1[slot] = umin32(b1[slot], hi);
            }
    };

    uint4 bufA[8], bufB[8];
    load_chunk(0, bufA);
    for (int g = 0; g < 16; g += 2) {
        if (g + 1 < 16) load_chunk(g + 1, bufB);   // in flight during bufA compute
        do_chunk(g, bufA);
        if (g + 2 < 16) load_chunk(g + 2, bufA);   // in flight during bufB compute
        if (g + 1 < 16) do_chunk(g + 1, bufB);
    }

#pragma unroll
    for (int m = 1; m <= 8; m <<= 1) {
#pragma unroll
        for (int s = 0; s < 16; ++s) {
            const uint32_t o0 = (uint32_t)__shfl_xor((int)b0[s], m);
            const uint32_t o1 = (uint32_t)__shfl_xor((int)b1[s], m);
            const uint32_t lo = umin32(b0[s], o0);
            const uint32_t hi = umax32(b0[s], o0);
            b0[s] = lo;
            b1[s] = umin32(umin32(b1[s], o1), hi);
        }
    }

    __syncthreads();
    uint32_t* ml = reinterpret_cast<uint32_t*>(As);   // [128 rows][4 wN][2]
    if (l15 == 0) {
#pragma unroll
        for (int s = 0; s < 16; ++s) {
            const int row = wM * 64 + (s >> 2) * 16 + kg * 4 + (s & 3);
            ml[(row * 4 + wN) * 2]     = b0[s];
            ml[(row * 4 + wN) * 2 + 1] = b1[s];
        }
    }
    __syncthreads();

    if (t < 128) {
        uint32_t k0 = 0xFFFFFFFFu, k1 = 0xFFFFFFFFu;
#pragma unroll
        for (int w = 0; w < 4; ++w) {
            const uint32_t a0 = ml[(t * 4 + w) * 2];
            const uint32_t a1 = ml[(t * 4 + w) * 2 + 1];
            const uint32_t lo = umin32(k0, a0);
            const uint32_t hi = umax32(k0, a0);
            k0 = lo;
            k1 = umin32(umin32(k1, a1), hi);
        }
        const int n = bidx * 128 + t;
        idxf[n] = (int)(k0 & 1023u);
        const float s0f = __uint_as_float(k0 & 0xFFFFFC00u);
        const float s1f = __uint_as_float(k1 & 0xFFFFFC00u);
        if (s1f - s0f < TAU2) {
            const int p = atomicAdd(count, 1);
            list[p] = n;
        }
    }
}

// ---------------------------------------------------------------------------
// kz: one-time compact gather of flagged z rows (validated rounds 13-16).
// ---------------------------------------------------------------------------
__global__ __launch_bounds__(256) void kz_gather(const float* __restrict__ z,
                                                 const int* __restrict__ list,
                                                 const int* __restrict__ count,
                                                 float* __restrict__ zc,
                                                 int cap) {
    const int cnt = min(*count, cap);
    const int total = cnt * 256;
    for (int idx = blockIdx.x * 256 + threadIdx.x; idx < total; idx += gridDim.x * 256) {
        const int i = idx >> 8, c = idx & 255;
        const int row = list[i];
        const int b = row >> 10, hw = row & 1023;
        zc[idx] = z[((size_t)(b * C_DIM + c)) * HW + hw];
    }
}

// ---------------------------------------------------------------------------
// kn: per-flagged-row faithful numpy-pairwise ||z||^2 (validated round 16).
// ---------------------------------------------------------------------------
__global__ __launch_bounds__(256) void kn_norm(const float* __restrict__ zc,
                                               const int* __restrict__ count,
                                               float* __restrict__ zn,
                                               int cap) {
    const int cnt = min(*count, cap);
    const int i = blockIdx.x * 256 + threadIdx.x;
    if (i >= cnt) return;
    const float* a = zc + (size_t)i * C_DIM;

    float blk[2];
#pragma unroll
    for (int h = 0; h < 2; ++h) {
        const float* p = a + h * 128;
        float4 v0 = *reinterpret_cast<const float4*>(p);
        float4 v1 = *reinterpret_cast<const float4*>(p + 4);
        float r[8];
        r[0] = __fmul_rn(v0.x, v0.x); r[1] = __fmul_rn(v0.y, v0.y);
        r[2] = __fmul_rn(v0.z, v0.z); r[3] = __fmul_rn(v0.w, v0.w);
        r[4] = __fmul_rn(v1.x, v1.x); r[5] = __fmul_rn(v1.y, v1.y);
        r[6] = __fmul_rn(v1.z, v1.z); r[7] = __fmul_rn(v1.w, v1.w);
        for (int q = 8; q < 128; q += 8) {
            float4 w0 = *reinterpret_cast<const float4*>(p + q);
            float4 w1 = *reinterpret_cast<const float4*>(p + q + 4);
            r[0] = __fadd_rn(r[0], __fmul_rn(w0.x, w0.x));
            r[1] = __fadd_rn(r[1], __fmul_rn(w0.y, w0.y));
            r[2] = __fadd_rn(r[2], __fmul_rn(w0.z, w0.z));
            r[3] = __fadd_rn(r[3], __fmul_rn(w0.w, w0.w));
            r[4] = __fadd_rn(r[4], __fmul_rn(w1.x, w1.x));
            r[5] = __fadd_rn(r[5], __fmul_rn(w1.y, w1.y));
            r[6] = __fadd_rn(r[6], __fmul_rn(w1.z, w1.z));
            r[7] = __fadd_rn(r[7], __fmul_rn(w1.w, w1.w));
        }
        blk[h] = __fadd_rn(__fadd_rn(__fadd_rn(r[0], r[1]), __fadd_rn(r[2], r[3])),
                           __fadd_rn(__fadd_rn(r[4], r[5]), __fadd_rn(r[6], r[7])));
    }
    zn[i] = __fadd_rn(blk[0], blk[1]);
}

// ---------------------------------------------------------------------------
// k3 v7: code-quarter-split faithful fp32 re-score (validated r12-16).
// ---------------------------------------------------------------------------
#define RB3 8
__global__ __launch_bounds__(256, 4) void k3_refine(const float* __restrict__ z,
                                                    const float* __restrict__ zc,
                                                    const float* __restrict__ zn,
                                                    const float* __restrict__ embT,
                                                    const float* __restrict__ Ef,
                                                    const int* __restrict__ list,
                                                    const int* __restrict__ count,
                                                    unsigned long long* __restrict__ slots,
                                                    int cap) {
    __shared__ __align__(16) float zs[C_DIM][RB3];   // 8 KB, [c][row]
    __shared__ int   rowsh[RB3];
    __shared__ float znsh[RB3];
    __shared__ unsigned long long wk[4][RB3];

    const int t = threadIdx.x;
    const int lane = t & 63, w = t >> 6;
    const int cnt = *count;
    const int ngroups = (cnt + RB3 - 1) / RB3;
    const int q = blockIdx.x & 3;
    const int code = q * 256 + t;

    for (int gi = blockIdx.x >> 2; gi < ngroups; gi += (gridDim.x >> 2)) {
        const int g0 = gi * RB3;
        const int nrows = min(RB3, cnt - g0);
        if (t < RB3) rowsh[t] = list[g0 + min(t, nrows - 1)];
        __syncthreads();

        {   // z rows -> zs[c][r]: compact path (L2) or strided fallback
            const int r = t & 7, cg = t >> 3;
            const int li = g0 + min(r, nrows - 1);
            if (li < cap) {
                const float* zp = zc + (size_t)li * C_DIM + cg * 8;
#pragma unroll
                for (int i = 0; i < 8; ++i)
                    zs[cg * 8 + i][r] = zp[i];
            } else {
                const int row = rowsh[r];
                const int b = row >> 10, hw = row & 1023;
                const float* zp = z + ((size_t)b * C_DIM + cg * 8) * HW + hw;
#pragma unroll
                for (int i = 0; i < 8; ++i)
                    zs[cg * 8 + i][r] = zp[(size_t)i * HW];
            }
        }
        __syncthreads();

        if (t < RB3) {
            const int li = g0 + min(t, nrows - 1);
            if (li < cap) {
                znsh[t] = zn[li];            // precomputed by kn
            } else {                          // fallback: serial faithful compute
                float blk[2];
#pragma unroll
                for (int h = 0; h < 2; ++h) {
                    float rr[8];
#pragma unroll
                    for (int j = 0; j < 8; ++j) {
                        const float v = zs[h * 128 + j][t];
                        rr[j] = __fmul_rn(v, v);
                    }
                    for (int i = 8; i < 128; i += 8) {
#pragma unroll
                        for (int j = 0; j < 8; ++j) {
                            const float v = zs[h * 128 + i + j][t];
                            rr[j] = __fadd_rn(rr[j], __fmul_rn(v, v));
                        }
                    }
                    blk[h] = __fadd_rn(__fadd_rn(__fadd_rn(rr[0], rr[1]), __fadd_rn(rr[2], rr[3])),
                                       __fadd_rn(__fadd_rn(rr[4], rr[5]), __fadd_rn(rr[6], rr[7])));
                }
                znsh[t] = __fadd_rn(blk[0], blk[1]);
            }
        }
        __syncthreads();

        float acc[RB3];
#pragma unroll
        for (int r = 0; r < RB3; ++r) acc[r] = 0.f;

        const float* ebase = embT + code;
#pragma unroll 8
        for (int c = 0; c < C_DIM; ++c) {
            const float ev = ebase[(size_t)c * K_CODES];
            float zv[RB3];
            *reinterpret_cast<float4*>(&zv[0]) = *reinterpret_cast<const float4*>(&zs[c][0]);
            *reinterpret_cast<float4*>(&zv[4]) = *reinterpret_cast<const float4*>(&zs[c][4]);
#pragma unroll
            for (int r = 0; r < RB3; ++r)
                acc[r] = __fmaf_rn(zv[r], ev, acc[r]);
        }

        const float ef = Ef[code];
        unsigned long long key[RB3];
#pragma unroll
        for (int r = 0; r < RB3; ++r) {
            const float dk = __fsub_rn(__fadd_rn(znsh[r], ef), __fmul_rn(2.0f, acc[r]));
            key[r] = ((unsigned long long)__float_as_uint(dk) << 32) | (unsigned int)code;
        }
#pragma unroll
        for (int m = 1; m <= 32; m <<= 1) {
#pragma unroll
            for (int r = 0; r < RB3; ++r) {
                const unsigned long long o = __shfl_xor(key[r], m);
                if (o < key[r]) key[r] = o;
            }
        }
        if (lane == 0) {
#pragma unroll
            for (int r = 0; r < RB3; ++r) wk[w][r] = key[r];
        }
        __syncthreads();
        if (t < RB3) {
            unsigned long long kk = wk[0][t];
#pragma unroll
            for (int ww = 1; ww < 4; ++ww)
                if (wk[ww][t] < kk) kk = wk[ww][t];
            if (t < nrows) atomicMin(&slots[rowsh[t]], kk);
        }
        __syncthreads();
    }
}

// ---------------------------------------------------------------------------
// k3b: write final indices for flagged rows from the u64 slots.
// ---------------------------------------------------------------------------
__global__ __launch_bounds__(256) void k3b_write(const int* __restrict__ list,
                                                 const int* __restrict__ count,
                                                 const unsigned long long* __restrict__ slots,
                                                 int* __restrict__ idxf) {
    const int cnt = *count;
    for (int i = blockIdx.x * 256 + threadIdx.x; i < cnt; i += gridDim.x * 256)
        idxf[list[i]] = (int)(slots[list[i]] & 1023ull);
}

// ---------------------------------------------------------------------------
// k4 v3: (c, b-quad) slab writer (validated rounds 15/16).
// ---------------------------------------------------------------------------
__global__ __launch_bounds__(256) void k4_out(const float* __restrict__ z,
                                              const float* __restrict__ embT,
                                              const int* __restrict__ idxf,
                                              float* __restrict__ out,
                                              double* __restrict__ pd) {
    const int t = threadIdx.x;
    const int c = blockIdx.x & 255, bq = blockIdx.x >> 8;   // bq in [0,8)
    const float* er = embT + (size_t)c * K_CODES;

    double acc = 0.0;
#pragma unroll
    for (int i = 0; i < 4; ++i) {
        const int b = bq * 4 + i;
        const size_t base = ((size_t)b * C_DIM + c) * HW + t * 4;
        const float4 zv = *reinterpret_cast<const float4*>(z + base);
        const int4  jv = *reinterpret_cast<const int4*>(idxf + b * HW + t * 4);
        const float e0 = er[jv.x], e1 = er[jv.y], e2 = er[jv.z], e3 = er[jv.w];

        float4 o;
        o.x = zv.x + (e0 - zv.x);
        o.y = zv.y + (e1 - zv.y);
        o.z = zv.z + (e2 - zv.z);
        o.w = zv.w + (e3 - zv.w);
        *reinterpret_cast<float4*>(out + base) = o;

        if (c == 0) {
            float4 fi;
            fi.x = (float)jv.x; fi.y = (float)jv.y; fi.z = (float)jv.z; fi.w = (float)jv.w;
            *reinterpret_cast<float4*>(out + (size_t)ZQ_ELEMS + 3 + b * HW + t * 4) = fi;
        }

        const double d0 = (double)e0 - (double)zv.x;
        const double d1 = (double)e1 - (double)zv.y;
        const double d2 = (double)e2 - (double)zv.z;
        const double d3 = (double)e3 - (double)zv.w;
        acc += d0 * d0 + d1 * d1 + d2 * d2 + d3 * d3;
    }

#pragma unroll
    for (int off = 32; off > 0; off >>= 1) acc += __shfl_down(acc, off);
    __shared__ double wsum[4];
    const int w = t >> 6, lanei = t & 63;
    if (lanei == 0) wsum[w] = acc;
    __syncthreads();
    if (t == 0) pd[blockIdx.x] = wsum[0] + wsum[1] + wsum[2] + wsum[3];
}

// ---------------------------------------------------------------------------
// k5: reduce the 2048 per-block partials (deterministic) + emit losses.
// ---------------------------------------------------------------------------
__global__ __launch_bounds__(256) void k5_loss(const double* __restrict__ pd,
                                               float* __restrict__ out) {
    const int t = threadIdx.x;
    double a = 0.0;
    for (int i = t; i < 2048; i += 256) a += pd[i];
#pragma unroll
    for (int off = 32; off > 0; off >>= 1) a += __shfl_down(a, off);
    __shared__ double wsum[4];
    const int w = t >> 6, lanei = t & 63;
    if (lanei == 0) wsum[w] = a;
    __syncthreads();
    if (t == 0) {
        const double m = (wsum[0] + wsum[1] + wsum[2] + wsum[3]) / (double)ZQ_ELEMS;
        const float cm = (float)(0.25 * m);
        const float cb = (float)m;
        out[ZQ_ELEMS]     = cm + cb;
        out[ZQ_ELEMS + 1] = cm;
        out[ZQ_ELEMS + 2] = cb;
    }
}

extern "C" void kernel_launch(void* const* d_in, const int* in_sizes, int n_in,
                              void* d_out, int out_size, void* d_ws, size_t ws_size,
                              hipStream_t stream) {
    const float* z   = (const float*)d_in[0];
    const float* emb = (const float*)d_in[1];
    float* out = (float*)d_out;
    char* ws = (char*)d_ws;

    float*  Ef    = (float*)(ws + OFF_EF);
    char*   Bb    = ws + OFF_BB;
    int*    idxf  = (int*)(ws + OFF_IDX);
    int*    list  = (int*)(ws + OFF_LIST);
    int*    count = (int*)(ws + OFF_COUNT);
    double* lsum  = (double*)(ws + OFF_LSUM);
    float*  embT  = (float*)(ws + OFF_ET);
    unsigned long long* slots = (unsigned long long*)(ws + OFF_SLOT);
    double* pd    = (double*)(ws + OFF_PD);
    float*  zn    = (float*)(ws + OFF_ZN);
    float*  zc    = (float*)(ws + OFF_ZC);

    int cap = 0;
    if (ws_size > (size_t)OFF_ZC + 1024)
        cap = (int)((ws_size - (size_t)OFF_ZC) / 1024);
    if (cap > NPOS) cap = NPOS;

    k1_prep<<<4, 256, 0, stream>>>(emb, Ef, Bb, count, lsum);
    k1t<<<64, 256, 0, stream>>>(emb, embT, slots);
    k2_gemm<<<256, 512, 0, stream>>>(z, Bb, Ef, idxf, list, count);
    kz_gather<<<1024, 256, 0, stream>>>(z, list, count, zc, cap);
    kn_norm<<<128, 256, 0, stream>>>(zc, count, zn, cap);
    k3_refine<<<4096, 256, 0, stream>>>(z, zc, zn, embT, Ef, list, count, slots, cap);
    k3b_write<<<64, 256, 0, stream>>>(list, count, slots, idxf);
    k4_out<<<2048, 256, 0, stream>>>(z, embT, idxf, out, pd);
    k5_loss<<<1, 256, 0, stream>>>(pd, out);
}

// Round 18
// 141.949 us; speedup vs baseline: 1.0590x; 1.0590x over previous
//
#include <hip/hip_runtime.h>

// Problem constants
#define C_DIM   256
#define K_CODES 1024
#define HW      1024
#define NPOS    32768            // B*H*W
#define ZQ_ELEMS 8388608         // B*C*H*W

typedef float  f32x4  __attribute__((ext_vector_type(4)));
typedef __bf16 bf16x8 __attribute__((ext_vector_type(8)));

// workspace byte offsets
#define OFF_EF    0                      // 1024 f32
#define OFF_BB    4096                   // 512 KB packed bf16 codebook image
#define OFF_IDX   (4096 + 524288)        // 32768 int
#define OFF_LIST  (OFF_IDX + 131072)     // 32768 int
#define OFF_COUNT (OFF_LIST + 131072)    // int
#define OFF_LSUM  (OFF_COUNT + 8)        // double
#define OFF_ET    790656                 // 1 MB f32 transposed codebook [c][k]
#define OFF_SLOT  1839232                // 256 KB u64 per-row argmin slots
#define OFF_PD    2101376                // 2048 doubles: per-block loss partials
#define OFF_ZN    2117760                // 32768 f32: per-flagged-row ||z||^2
#define OFF_ZC    2248832                // compact z rows for flagged list (cap'd by ws)

// flag margin (validated rounds 11-17 at 4e-4)
#define TAU2 4e-4f

static __device__ __forceinline__ uint32_t umin32(uint32_t a, uint32_t b) { return a < b ? a : b; }
static __device__ __forceinline__ uint32_t umax32(uint32_t a, uint32_t b) { return a > b ? a : b; }

// ---------------------------------------------------------------------------
// k1: faithful fp32 ||e_k||^2 (numpy pairwise emulation, validated round 2)
//     + pack codebook to chunk-linear swizzled bf16 image Bb + init scalars.
// ---------------------------------------------------------------------------
__global__ __launch_bounds__(256) void k1_prep(const float* __restrict__ emb,
                                               float* __restrict__ Ef,
                                               char* __restrict__ Bb,
                                               int* __restrict__ count,
                                               double* __restrict__ lsum) {
    const int k = blockIdx.x * 256 + threadIdx.x;
    if (k == 0) { *count = 0; *lsum = 0.0; }
    const float* a = emb + (size_t)k * C_DIM;

    float blk[2];
#pragma unroll
    for (int h = 0; h < 2; ++h) {
        const float* p = a + h * 128;
        float4 v0 = *reinterpret_cast<const float4*>(p);
        float4 v1 = *reinterpret_cast<const float4*>(p + 4);
        float r[8];
        r[0] = __fmul_rn(v0.x, v0.x); r[1] = __fmul_rn(v0.y, v0.y);
        r[2] = __fmul_rn(v0.z, v0.z); r[3] = __fmul_rn(v0.w, v0.w);
        r[4] = __fmul_rn(v1.x, v1.x); r[5] = __fmul_rn(v1.y, v1.y);
        r[6] = __fmul_rn(v1.z, v1.z); r[7] = __fmul_rn(v1.w, v1.w);
        for (int i = 8; i < 128; i += 8) {
            float4 w0 = *reinterpret_cast<const float4*>(p + i);
            float4 w1 = *reinterpret_cast<const float4*>(p + i + 4);
            r[0] = __fadd_rn(r[0], __fmul_rn(w0.x, w0.x));
            r[1] = __fadd_rn(r[1], __fmul_rn(w0.y, w0.y));
            r[2] = __fadd_rn(r[2], __fmul_rn(w0.z, w0.z));
            r[3] = __fadd_rn(r[3], __fmul_rn(w0.w, w0.w));
            r[4] = __fadd_rn(r[4], __fmul_rn(w1.x, w1.x));
            r[5] = __fadd_rn(r[5], __fmul_rn(w1.y, w1.y));
            r[6] = __fadd_rn(r[6], __fmul_rn(w1.z, w1.z));
            r[7] = __fadd_rn(r[7], __fmul_rn(w1.w, w1.w));
        }
        blk[h] = __fadd_rn(__fadd_rn(__fadd_rn(r[0], r[1]), __fadd_rn(r[2], r[3])),
                           __fadd_rn(__fadd_rn(r[4], r[5]), __fadd_rn(r[6], r[7])));
    }
    Ef[k] = __fadd_rn(blk[0], blk[1]);

    const int r = k & 63, chunk = k >> 6;
    const int xr = ((r ^ (r >> 2)) & 3) << 4;
    char* base = Bb + (size_t)chunk * 32768 + r * 64;
#pragma unroll
    for (int s = 0; s < 8; ++s) {
        const float* ep = a + s * 32;
        char* sb = base + s * 4096;
#pragma unroll
        for (int g = 0; g < 4; ++g) {
            union { __bf16 h[8]; uint4 v; } pk;
#pragma unroll
            for (int j = 0; j < 8; ++j) pk.h[j] = (__bf16)ep[g * 8 + j];
            *reinterpret_cast<uint4*>(sb + ((g * 16) ^ xr)) = pk.v;
        }
    }
}

// ---------------------------------------------------------------------------
// k1t: codebook transpose (validated round 8) + init u64 argmin slots.
// ---------------------------------------------------------------------------
__global__ __launch_bounds__(256) void k1t(const float* __restrict__ emb,
                                           float* __restrict__ embT,
                                           unsigned long long* __restrict__ slots) {
    const int tid = blockIdx.x * 256 + threadIdx.x;
    slots[tid * 2]     = ~0ull;
    slots[tid * 2 + 1] = ~0ull;

    __shared__ float tile[64][65];
    const int l = threadIdx.x & 63, w = threadIdx.x >> 6;
    const int k0 = (blockIdx.x & 15) * 64;
    const int c0 = (blockIdx.x >> 4) * 64;
#pragma unroll
    for (int i = 0; i < 16; ++i)
        tile[l][w * 16 + i] = emb[(size_t)(k0 + w * 16 + i) * C_DIM + c0 + l];
    __syncthreads();
#pragma unroll
    for (int i = 0; i < 16; ++i)
        embT[(size_t)(c0 + w * 16 + i) * K_CODES + k0 + l] = tile[w * 16 + i][l];
}

// ---------------------------------------------------------------------------
// k2 v5: barrier-free MFMA scoring GEMM, 64-row tile / 512 blocks for TLP
// (2-3 blocks per CU hide B-load latency). Loads inline (r16-style, no
// register double-buffer -- r17's spilled). Numerics/epilogue identical.
// ---------------------------------------------------------------------------
__global__ __launch_bounds__(512, 2) void k2_gemm(const float* __restrict__ z,
                                                  const char* __restrict__ Bb,
                                                  const float* __restrict__ Ef,
                                                  int* __restrict__ idxf,
                                                  int* __restrict__ list,
                                                  int* __restrict__ count) {
    __shared__ char As[32768];             // A image (64 rows x 512B); merge reuses

    const int t    = threadIdx.x;
    const int bidx = blockIdx.x;
    const int lane = t & 63;
    const int l15  = lane & 15, kg = lane >> 4;
    const int wid  = t >> 6;
    const int wM   = wid >> 2, wN = wid & 3;   // 2M x 4N waves; wave tile 32 rows

    // ---- A fill: transpose 64-row z tile -> As[hw][c] bf16, swizzled ----
    const float* zt = z + (size_t)(bidx >> 4) * (C_DIM * HW) + (bidx & 15) * 64;
#pragma unroll
    for (int p = 0; p < 4; ++p) {
        const int pi  = p * 512 + t;         // [0, 2048)
        const int c2  = pi >> 4;             // c-pair 0..127
        const int hwg = pi & 15;             // 0..15
        const float* p0 = zt + (size_t)(2 * c2) * HW + hwg * 4;
        const float4 f0 = *reinterpret_cast<const float4*>(p0);
        const float4 f1 = *reinterpret_cast<const float4*>(p0 + HW);
        const float a0v[4] = {f0.x, f0.y, f0.z, f0.w};
        const float a1v[4] = {f1.x, f1.y, f1.z, f1.w};
#pragma unroll
        for (int i = 0; i < 4; ++i) {
            const int hw = hwg * 4 + i;      // 0..63
            const int xr = ((hw ^ (hw >> 2)) & 7) << 4;
            const int koff = (c2 * 4) ^ xr;
            union { __bf16 h[2]; unsigned int u; } ph;
            ph.h[0] = (__bf16)a0v[i];
            ph.h[1] = (__bf16)a1v[i];
            *reinterpret_cast<unsigned int*>(As + hw * 512 + koff) = ph.u;
        }
    }
    __syncthreads();

    // ---- hoist A fragments (validated layout), mi = 0..1 ----
    bf16x8 af[2][8];
#pragma unroll
    for (int mi = 0; mi < 2; ++mi) {
        const int row = wM * 32 + mi * 16 + l15;
        const int axr = ((row ^ (row >> 2)) & 7) << 4;
#pragma unroll
        for (int ks = 0; ks < 8; ++ks)
            af[mi][ks] = *reinterpret_cast<const bf16x8*>(
                As + row * 512 + ((ks * 64 + kg * 16) ^ axr));
    }

    const int rB  = wN * 16 + l15;               // code within chunk
    const int swz = ((rB ^ (rB >> 2)) & 3) << 4;
    const size_t voff = (size_t)rB * 64 + ((kg * 16) ^ swz);

    uint32_t b0[8], b1[8];
#pragma unroll
    for (int s = 0; s < 8; ++s) { b0[s] = 0xFFFFFFFFu; b1[s] = 0xFFFFFFFFu; }

    for (int g = 0; g < 16; ++g) {
        const char* bgp = Bb + (size_t)g * 32768 + voff;
        union { uint4 u; bf16x8 b; } ld[8];
#pragma unroll
        for (int ks = 0; ks < 8; ++ks)
            ld[ks].u = *reinterpret_cast<const uint4*>(bgp + ks * 4096);

        const float efb = Ef[g * 64 + rB] + 0.5f;

        f32x4 acc[2];
#pragma unroll
        for (int mi = 0; mi < 2; ++mi) acc[mi] = f32x4{0.f, 0.f, 0.f, 0.f};
#pragma unroll
        for (int ks = 0; ks < 8; ++ks)
#pragma unroll
            for (int mi = 0; mi < 2; ++mi)
                acc[mi] = __builtin_amdgcn_mfma_f32_16x16x32_bf16(
                    af[mi][ks], ld[ks].b, acc[mi], 0, 0, 0);

        const uint32_t code = (uint32_t)(g * 64 + rB);
#pragma unroll
        for (int mi = 0; mi < 2; ++mi)
#pragma unroll
            for (int rr = 0; rr < 4; ++rr) {
                const float sp = __fmaf_rn(acc[mi][rr], -2.0f, efb);
                const uint32_t key = (__float_as_uint(sp) & 0xFFFFFC00u) | code;
                const int slot = mi * 4 + rr;
                const uint32_t lo = umin32(b0[slot], key);
                const uint32_t hi = umax32(b0[slot], key);
                b0[slot] = lo;
                b1[slot] = umin32(b1[slot], hi);
            }
    }

    // ---- top-2 merge across the 16 column-lanes (same kg group) ----
#pragma unroll
    for (int m = 1; m <= 8; m <<= 1) {
#pragma unroll
        for (int s = 0; s < 8; ++s) {
            const uint32_t o0 = (uint32_t)__shfl_xor((int)b0[s], m);
            const uint32_t o1 = (uint32_t)__shfl_xor((int)b1[s], m);
            const uint32_t lo = umin32(b0[s], o0);
            const uint32_t hi = umax32(b0[s], o0);
            b0[s] = lo;
            b1[s] = umin32(umin32(b1[s], o1), hi);
        }
    }

    // ---- cross-wN merge via LDS (As is dead) ----
    __syncthreads();
    uint32_t* ml = reinterpret_cast<uint32_t*>(As);   // [64 rows][4 wN][2]
    if (l15 == 0) {
#pragma unroll
        for (int s = 0; s < 8; ++s) {
            const int row = wM * 32 + (s >> 2) * 16 + kg * 4 + (s & 3);
            ml[(row * 4 + wN) * 2]     = b0[s];
            ml[(row * 4 + wN) * 2 + 1] = b1[s];
        }
    }
    __syncthreads();

    if (t < 64) {
        uint32_t k0 = 0xFFFFFFFFu, k1 = 0xFFFFFFFFu;
#pragma unroll
        for (int w = 0; w < 4; ++w) {
            const uint32_t a0 = ml[(t * 4 + w) * 2];
            const uint32_t a1 = ml[(t * 4 + w) * 2 + 1];
            const uint32_t lo = umin32(k0, a0);
            const uint32_t hi = umax32(k0, a0);
            k0 = lo;
            k1 = umin32(umin32(k1, a1), hi);
        }
        const int n = bidx * 64 + t;
        idxf[n] = (int)(k0 & 1023u);
        const float s0f = __uint_as_float(k0 & 0xFFFFFC00u);
        const float s1f = __uint_as_float(k1 & 0xFFFFFC00u);
        if (s1f - s0f < TAU2) {
            const int p = atomicAdd(count, 1);
            list[p] = n;
        }
    }
}

// ---------------------------------------------------------------------------
// kz: one-time compact gather of flagged z rows (validated rounds 13-17).
// ---------------------------------------------------------------------------
__global__ __launch_bounds__(256) void kz_gather(const float* __restrict__ z,
                                                 const int* __restrict__ list,
                                                 const int* __restrict__ count,
                                                 float* __restrict__ zc,
                                                 int cap) {
    const int cnt = min(*count, cap);
    const int total = cnt * 256;
    for (int idx = blockIdx.x * 256 + threadIdx.x; idx < total; idx += gridDim.x * 256) {
        const int i = idx >> 8, c = idx & 255;
        const int row = list[i];
        const int b = row >> 10, hw = row & 1023;
        zc[idx] = z[((size_t)(b * C_DIM + c)) * HW + hw];
    }
}

// ---------------------------------------------------------------------------
// kn: per-flagged-row faithful numpy-pairwise ||z||^2 (validated round 16).
// ---------------------------------------------------------------------------
__global__ __launch_bounds__(256) void kn_norm(const float* __restrict__ zc,
                                               const int* __restrict__ count,
                                               float* __restrict__ zn,
                                               int cap) {
    const int cnt = min(*count, cap);
    const int i = blockIdx.x * 256 + threadIdx.x;
    if (i >= cnt) return;
    const float* a = zc + (size_t)i * C_DIM;

    float blk[2];
#pragma unroll
    for (int h = 0; h < 2; ++h) {
        const float* p = a + h * 128;
        float4 v0 = *reinterpret_cast<const float4*>(p);
        float4 v1 = *reinterpret_cast<const float4*>(p + 4);
        float r[8];
        r[0] = __fmul_rn(v0.x, v0.x); r[1] = __fmul_rn(v0.y, v0.y);
        r[2] = __fmul_rn(v0.z, v0.z); r[3] = __fmul_rn(v0.w, v0.w);
        r[4] = __fmul_rn(v1.x, v1.x); r[5] = __fmul_rn(v1.y, v1.y);
        r[6] = __fmul_rn(v1.z, v1.z); r[7] = __fmul_rn(v1.w, v1.w);
        for (int q = 8; q < 128; q += 8) {
            float4 w0 = *reinterpret_cast<const float4*>(p + q);
            float4 w1 = *reinterpret_cast<const float4*>(p + q + 4);
            r[0] = __fadd_rn(r[0], __fmul_rn(w0.x, w0.x));
            r[1] = __fadd_rn(r[1], __fmul_rn(w0.y, w0.y));
            r[2] = __fadd_rn(r[2], __fmul_rn(w0.z, w0.z));
            r[3] = __fadd_rn(r[3], __fmul_rn(w0.w, w0.w));
            r[4] = __fadd_rn(r[4], __fmul_rn(w1.x, w1.x));
            r[5] = __fadd_rn(r[5], __fmul_rn(w1.y, w1.y));
            r[6] = __fadd_rn(r[6], __fmul_rn(w1.z, w1.z));
            r[7] = __fadd_rn(r[7], __fmul_rn(w1.w, w1.w));
        }
        blk[h] = __fadd_rn(__fadd_rn(__fadd_rn(r[0], r[1]), __fadd_rn(r[2], r[3])),
                           __fadd_rn(__fadd_rn(r[4], r[5]), __fadd_rn(r[6], r[7])));
    }
    zn[i] = __fadd_rn(blk[0], blk[1]);
}

// ---------------------------------------------------------------------------
// k3 v7: code-quarter-split faithful fp32 re-score (validated r12-17).
// ---------------------------------------------------------------------------
#define RB3 8
__global__ __launch_bounds__(256, 4) void k3_refine(const float* __restrict__ z,
                                                    const float* __restrict__ zc,
                                                    const float* __restrict__ zn,
                                                    const float* __restrict__ embT,
                                                    const float* __restrict__ Ef,
                                                    const int* __restrict__ list,
                                                    const int* __restrict__ count,
                                                    unsigned long long* __restrict__ slots,
                                                    int cap) {
    __shared__ __align__(16) float zs[C_DIM][RB3];   // 8 KB, [c][row]
    __shared__ int   rowsh[RB3];
    __shared__ float znsh[RB3];
    __shared__ unsigned long long wk[4][RB3];

    const int t = threadIdx.x;
    const int lane = t & 63, w = t >> 6;
    const int cnt = *count;
    const int ngroups = (cnt + RB3 - 1) / RB3;
    const int q = blockIdx.x & 3;
    const int code = q * 256 + t;

    for (int gi = blockIdx.x >> 2; gi < ngroups; gi += (gridDim.x >> 2)) {
        const int g0 = gi * RB3;
        const int nrows = min(RB3, cnt - g0);
        if (t < RB3) rowsh[t] = list[g0 + min(t, nrows - 1)];
        __syncthreads();

        {   // z rows -> zs[c][r]: compact path (L2) or strided fallback
            const int r = t & 7, cg = t >> 3;
            const int li = g0 + min(r, nrows - 1);
            if (li < cap) {
                const float* zp = zc + (size_t)li * C_DIM + cg * 8;
#pragma unroll
                for (int i = 0; i < 8; ++i)
                    zs[cg * 8 + i][r] = zp[i];
            } else {
                const int row = rowsh[r];
                const int b = row >> 10, hw = row & 1023;
                const float* zp = z + ((size_t)b * C_DIM + cg * 8) * HW + hw;
#pragma unroll
                for (int i = 0; i < 8; ++i)
                    zs[cg * 8 + i][r] = zp[(size_t)i * HW];
            }
        }
        __syncthreads();

        if (t < RB3) {
            const int li = g0 + min(t, nrows - 1);
            if (li < cap) {
                znsh[t] = zn[li];            // precomputed by kn
            } else {                          // fallback: serial faithful compute
                float blk[2];
#pragma unroll
                for (int h = 0; h < 2; ++h) {
                    float rr[8];
#pragma unroll
                    for (int j = 0; j < 8; ++j) {
                        const float v = zs[h * 128 + j][t];
                        rr[j] = __fmul_rn(v, v);
                    }
                    for (int i = 8; i < 128; i += 8) {
#pragma unroll
                        for (int j = 0; j < 8; ++j) {
                            const float v = zs[h * 128 + i + j][t];
                            rr[j] = __fadd_rn(rr[j], __fmul_rn(v, v));
                        }
                    }
                    blk[h] = __fadd_rn(__fadd_rn(__fadd_rn(rr[0], rr[1]), __fadd_rn(rr[2], rr[3])),
                                       __fadd_rn(__fadd_rn(rr[4], rr[5]), __fadd_rn(rr[6], rr[7])));
                }
                znsh[t] = __fadd_rn(blk[0], blk[1]);
            }
        }
        __syncthreads();

        float acc[RB3];
#pragma unroll
        for (int r = 0; r < RB3; ++r) acc[r] = 0.f;

        const float* ebase = embT + code;
#pragma unroll 8
        for (int c = 0; c < C_DIM; ++c) {
            const float ev = ebase[(size_t)c * K_CODES];
            float zv[RB3];
            *reinterpret_cast<float4*>(&zv[0]) = *reinterpret_cast<const float4*>(&zs[c][0]);
            *reinterpret_cast<float4*>(&zv[4]) = *reinterpret_cast<const float4*>(&zs[c][4]);
#pragma unroll
            for (int r = 0; r < RB3; ++r)
                acc[r] = __fmaf_rn(zv[r], ev, acc[r]);
        }

        const float ef = Ef[code];
        unsigned long long key[RB3];
#pragma unroll
        for (int r = 0; r < RB3; ++r) {
            const float dk = __fsub_rn(__fadd_rn(znsh[r], ef), __fmul_rn(2.0f, acc[r]));
            key[r] = ((unsigned long long)__float_as_uint(dk) << 32) | (unsigned int)code;
        }
#pragma unroll
        for (int m = 1; m <= 32; m <<= 1) {
#pragma unroll
            for (int r = 0; r < RB3; ++r) {
                const unsigned long long o = __shfl_xor(key[r], m);
                if (o < key[r]) key[r] = o;
            }
        }
        if (lane == 0) {
#pragma unroll
            for (int r = 0; r < RB3; ++r) wk[w][r] = key[r];
        }
        __syncthreads();
        if (t < RB3) {
            unsigned long long kk = wk[0][t];
#pragma unroll
            for (int ww = 1; ww < 4; ++ww)
                if (wk[ww][t] < kk) kk = wk[ww][t];
            if (t < nrows) atomicMin(&slots[rowsh[t]], kk);
        }
        __syncthreads();
    }
}

// ---------------------------------------------------------------------------
// k3b: write final indices for flagged rows from the u64 slots.
// ---------------------------------------------------------------------------
__global__ __launch_bounds__(256) void k3b_write(const int* __restrict__ list,
                                                 const int* __restrict__ count,
                                                 const unsigned long long* __restrict__ slots,
                                                 int* __restrict__ idxf) {
    const int cnt = *count;
    for (int i = blockIdx.x * 256 + threadIdx.x; i < cnt; i += gridDim.x * 256)
        idxf[list[i]] = (int)(slots[list[i]] & 1023ull);
}

// ---------------------------------------------------------------------------
// k4 v3: (c, b-quad) slab writer (validated rounds 15-17).
// ---------------------------------------------------------------------------
__global__ __launch_bounds__(256) void k4_out(const float* __restrict__ z,
                                              const float* __restrict__ embT,
                                              const int* __restrict__ idxf,
                                              float* __restrict__ out,
                                              double* __restrict__ pd) {
    const int t = threadIdx.x;
    const int c = blockIdx.x & 255, bq = blockIdx.x >> 8;   // bq in [0,8)
    const float* er = embT + (size_t)c * K_CODES;

    double acc = 0.0;
#pragma unroll
    for (int i = 0; i < 4; ++i) {
        const int b = bq * 4 + i;
        const size_t base = ((size_t)b * C_DIM + c) * HW + t * 4;
        const float4 zv = *reinterpret_cast<const float4*>(z + base);
        const int4  jv = *reinterpret_cast<const int4*>(idxf + b * HW + t * 4);
        const float e0 = er[jv.x], e1 = er[jv.y], e2 = er[jv.z], e3 = er[jv.w];

        float4 o;
        o.x = zv.x + (e0 - zv.x);
        o.y = zv.y + (e1 - zv.y);
        o.z = zv.z + (e2 - zv.z);
        o.w = zv.w + (e3 - zv.w);
        *reinterpret_cast<float4*>(out + base) = o;

        if (c == 0) {
            float4 fi;
            fi.x = (float)jv.x; fi.y = (float)jv.y; fi.z = (float)jv.z; fi.w = (float)jv.w;
            *reinterpret_cast<float4*>(out + (size_t)ZQ_ELEMS + 3 + b * HW + t * 4) = fi;
        }

        const double d0 = (double)e0 - (double)zv.x;
        const double d1 = (double)e1 - (double)zv.y;
        const double d2 = (double)e2 - (double)zv.z;
        const double d3 = (double)e3 - (double)zv.w;
        acc += d0 * d0 + d1 * d1 + d2 * d2 + d3 * d3;
    }

#pragma unroll
    for (int off = 32; off > 0; off >>= 1) acc += __shfl_down(acc, off);
    __shared__ double wsum[4];
    const int w = t >> 6, lanei = t & 63;
    if (lanei == 0) wsum[w] = acc;
    __syncthreads();
    if (t == 0) pd[blockIdx.x] = wsum[0] + wsum[1] + wsum[2] + wsum[3];
}

// ---------------------------------------------------------------------------
// k5: reduce the 2048 per-block partials (deterministic) + emit losses.
// ---------------------------------------------------------------------------
__global__ __launch_bounds__(256) void k5_loss(const double* __restrict__ pd,
                                               float* __restrict__ out) {
    const int t = threadIdx.x;
    double a = 0.0;
    for (int i = t; i < 2048; i += 256) a += pd[i];
#pragma unroll
    for (int off = 32; off > 0; off >>= 1) a += __shfl_down(a, off);
    __shared__ double wsum[4];
    const int w = t >> 6, lanei = t & 63;
    if (lanei == 0) wsum[w] = a;
    __syncthreads();
    if (t == 0) {
        const double m = (wsum[0] + wsum[1] + wsum[2] + wsum[3]) / (double)ZQ_ELEMS;
        const float cm = (float)(0.25 * m);
        const float cb = (float)m;
        out[ZQ_ELEMS]     = cm + cb;
        out[ZQ_ELEMS + 1] = cm;
        out[ZQ_ELEMS + 2] = cb;
    }
}

extern "C" void kernel_launch(void* const* d_in, const int* in_sizes, int n_in,
                              void* d_out, int out_size, void* d_ws, size_t ws_size,
                              hipStream_t stream) {
    const float* z   = (const float*)d_in[0];
    const float* emb = (const float*)d_in[1];
    float* out = (float*)d_out;
    char* ws = (char*)d_ws;

    float*  Ef    = (float*)(ws + OFF_EF);
    char*   Bb    = ws + OFF_BB;
    int*    idxf  = (int*)(ws + OFF_IDX);
    int*    list  = (int*)(ws + OFF_LIST);
    int*    count = (int*)(ws + OFF_COUNT);
    double* lsum  = (double*)(ws + OFF_LSUM);
    float*  embT  = (float*)(ws + OFF_ET);
    unsigned long long* slots = (unsigned long long*)(ws + OFF_SLOT);
    double* pd    = (double*)(ws + OFF_PD);
    float*  zn    = (float*)(ws + OFF_ZN);
    float*  zc    = (float*)(ws + OFF_ZC);

    int cap = 0;
    if (ws_size > (size_t)OFF_ZC + 1024)
        cap = (int)((ws_size - (size_t)OFF_ZC) / 1024);
    if (cap > NPOS) cap = NPOS;

    k1_prep<<<4, 256, 0, stream>>>(emb, Ef, Bb, count, lsum);
    k1t<<<64, 256, 0, stream>>>(emb, embT, slots);
    k2_gemm<<<512, 512, 0, stream>>>(z, Bb, Ef, idxf, list, count);
    kz_gather<<<1024, 256, 0, stream>>>(z, list, count, zc, cap);
    kn_norm<<<128, 256, 0, stream>>>(zc, count, zn, cap);
    k3_refine<<<4096, 256, 0, stream>>>(z, zc, zn, embT, Ef, list, count, slots, cap);
    k3b_write<<<64, 256, 0, stream>>>(list, count, slots, idxf);
    k4_out<<<2048, 256, 0, stream>>>(z, embT, idxf, out, pd);
    k5_loss<<<1, 256, 0, stream>>>(pd, out);
}

// Round 19
// 126.649 us; speedup vs baseline: 1.1869x; 1.1208x over previous
//
#include <hip/hip_runtime.h>

// Problem constants
#define C_DIM   256
#define K_CODES 1024
#define HW      1024
#define NPOS    32768            // B*H*W
#define ZQ_ELEMS 8388608         // B*C*H*W

typedef float  f32x4  __attribute__((ext_vector_type(4)));
typedef __bf16 bf16x8 __attribute__((ext_vector_type(8)));

// workspace byte offsets
#define OFF_EF    0                      // 1024 f32
#define OFF_BB    4096                   // 512 KB packed bf16 codebook image
#define OFF_IDX   (4096 + 524288)        // 32768 int
#define OFF_LIST  (OFF_IDX + 131072)     // 32768 int
#define OFF_COUNT (OFF_LIST + 131072)    // int
#define OFF_LSUM  (OFF_COUNT + 8)        // double
#define OFF_ET    790656                 // 1 MB f32 transposed codebook [c][k]
#define OFF_SLOT  1839232                // 256 KB u64 per-row argmin slots
#define OFF_PD    2101376                // 2048 doubles: per-block loss partials
#define OFF_ZN    2117760                // 32768 f32: per-flagged-row ||z||^2
#define OFF_ZC    2248832                // compact z rows for flagged list (cap'd by ws)

// flag margin (validated rounds 11-18 at 4e-4)
#define TAU2 4e-4f

static __device__ __forceinline__ uint32_t umin32(uint32_t a, uint32_t b) { return a < b ? a : b; }
static __device__ __forceinline__ uint32_t umax32(uint32_t a, uint32_t b) { return a > b ? a : b; }

// ---------------------------------------------------------------------------
// kprep: fused k1_prep + k1t (both consume only emb).
//  blocks 0-3 : faithful fp32 ||e_k||^2 (numpy pairwise, validated r2) +
//               chunk-linear swizzled bf16 codebook image Bb + scalars init.
//  all blocks : 64x64 tile transpose emb -> embT + u64 slot init.
// ---------------------------------------------------------------------------
__global__ __launch_bounds__(256) void kprep(const float* __restrict__ emb,
                                             float* __restrict__ Ef,
                                             char* __restrict__ Bb,
                                             int* __restrict__ count,
                                             double* __restrict__ lsum,
                                             float* __restrict__ embT,
                                             unsigned long long* __restrict__ slots) {
    const int tid = blockIdx.x * 256 + threadIdx.x;
    slots[tid * 2]     = ~0ull;
    slots[tid * 2 + 1] = ~0ull;
    if (tid == 0) { *count = 0; *lsum = 0.0; }

    if (blockIdx.x < 4) {
        const int k = tid;
        const float* a = emb + (size_t)k * C_DIM;

        float blk[2];
#pragma unroll
        for (int h = 0; h < 2; ++h) {
            const float* p = a + h * 128;
            float4 v0 = *reinterpret_cast<const float4*>(p);
            float4 v1 = *reinterpret_cast<const float4*>(p + 4);
            float r[8];
            r[0] = __fmul_rn(v0.x, v0.x); r[1] = __fmul_rn(v0.y, v0.y);
            r[2] = __fmul_rn(v0.z, v0.z); r[3] = __fmul_rn(v0.w, v0.w);
            r[4] = __fmul_rn(v1.x, v1.x); r[5] = __fmul_rn(v1.y, v1.y);
            r[6] = __fmul_rn(v1.z, v1.z); r[7] = __fmul_rn(v1.w, v1.w);
            for (int i = 8; i < 128; i += 8) {
                float4 w0 = *reinterpret_cast<const float4*>(p + i);
                float4 w1 = *reinterpret_cast<const float4*>(p + i + 4);
                r[0] = __fadd_rn(r[0], __fmul_rn(w0.x, w0.x));
                r[1] = __fadd_rn(r[1], __fmul_rn(w0.y, w0.y));
                r[2] = __fadd_rn(r[2], __fmul_rn(w0.z, w0.z));
                r[3] = __fadd_rn(r[3], __fmul_rn(w0.w, w0.w));
                r[4] = __fadd_rn(r[4], __fmul_rn(w1.x, w1.x));
                r[5] = __fadd_rn(r[5], __fmul_rn(w1.y, w1.y));
                r[6] = __fadd_rn(r[6], __fmul_rn(w1.z, w1.z));
                r[7] = __fadd_rn(r[7], __fmul_rn(w1.w, w1.w));
            }
            blk[h] = __fadd_rn(__fadd_rn(__fadd_rn(r[0], r[1]), __fadd_rn(r[2], r[3])),
                               __fadd_rn(__fadd_rn(r[4], r[5]), __fadd_rn(r[6], r[7])));
        }
        Ef[k] = __fadd_rn(blk[0], blk[1]);

        const int rr2 = k & 63, chunk = k >> 6;
        const int xr = ((rr2 ^ (rr2 >> 2)) & 3) << 4;
        char* base = Bb + (size_t)chunk * 32768 + rr2 * 64;
#pragma unroll
        for (int s = 0; s < 8; ++s) {
            const float* ep = a + s * 32;
            char* sb = base + s * 4096;
#pragma unroll
            for (int g = 0; g < 4; ++g) {
                union { __bf16 h[8]; uint4 v; } pk;
#pragma unroll
                for (int j = 0; j < 8; ++j) pk.h[j] = (__bf16)ep[g * 8 + j];
                *reinterpret_cast<uint4*>(sb + ((g * 16) ^ xr)) = pk.v;
            }
        }
    }

    // --- transpose tile (all 64 blocks; validated round 8) ---
    __shared__ float tile[64][65];
    const int l = threadIdx.x & 63, w = threadIdx.x >> 6;
    const int k0 = (blockIdx.x & 15) * 64;
    const int c0 = (blockIdx.x >> 4) * 64;
#pragma unroll
    for (int i = 0; i < 16; ++i)
        tile[l][w * 16 + i] = emb[(size_t)(k0 + w * 16 + i) * C_DIM + c0 + l];
    __syncthreads();
#pragma unroll
    for (int i = 0; i < 16; ++i)
        embT[(size_t)(c0 + w * 16 + i) * K_CODES + k0 + l] = tile[w * 16 + i][l];
}

// ---------------------------------------------------------------------------
// k2 v5: barrier-free MFMA scoring GEMM, 64-row tile / 512 blocks
// (validated round 18, unchanged).
// ---------------------------------------------------------------------------
__global__ __launch_bounds__(512, 2) void k2_gemm(const float* __restrict__ z,
                                                  const char* __restrict__ Bb,
                                                  const float* __restrict__ Ef,
                                                  int* __restrict__ idxf,
                                                  int* __restrict__ list,
                                                  int* __restrict__ count) {
    __shared__ char As[32768];             // A image (64 rows x 512B); merge reuses

    const int t    = threadIdx.x;
    const int bidx = blockIdx.x;
    const int lane = t & 63;
    const int l15  = lane & 15, kg = lane >> 4;
    const int wid  = t >> 6;
    const int wM   = wid >> 2, wN = wid & 3;   // 2M x 4N waves; wave tile 32 rows

    const float* zt = z + (size_t)(bidx >> 4) * (C_DIM * HW) + (bidx & 15) * 64;
#pragma unroll
    for (int p = 0; p < 4; ++p) {
        const int pi  = p * 512 + t;
        const int c2  = pi >> 4;
        const int hwg = pi & 15;
        const float* p0 = zt + (size_t)(2 * c2) * HW + hwg * 4;
        const float4 f0 = *reinterpret_cast<const float4*>(p0);
        const float4 f1 = *reinterpret_cast<const float4*>(p0 + HW);
        const float a0v[4] = {f0.x, f0.y, f0.z, f0.w};
        const float a1v[4] = {f1.x, f1.y, f1.z, f1.w};
#pragma unroll
        for (int i = 0; i < 4; ++i) {
            const int hw = hwg * 4 + i;
            const int xr = ((hw ^ (hw >> 2)) & 7) << 4;
            const int koff = (c2 * 4) ^ xr;
            union { __bf16 h[2]; unsigned int u; } ph;
            ph.h[0] = (__bf16)a0v[i];
            ph.h[1] = (__bf16)a1v[i];
            *reinterpret_cast<unsigned int*>(As + hw * 512 + koff) = ph.u;
        }
    }
    __syncthreads();

    bf16x8 af[2][8];
#pragma unroll
    for (int mi = 0; mi < 2; ++mi) {
        const int row = wM * 32 + mi * 16 + l15;
        const int axr = ((row ^ (row >> 2)) & 7) << 4;
#pragma unroll
        for (int ks = 0; ks < 8; ++ks)
            af[mi][ks] = *reinterpret_cast<const bf16x8*>(
                As + row * 512 + ((ks * 64 + kg * 16) ^ axr));
    }

    const int rB  = wN * 16 + l15;
    const int swz = ((rB ^ (rB >> 2)) & 3) << 4;
    const size_t voff = (size_t)rB * 64 + ((kg * 16) ^ swz);

    uint32_t b0[8], b1[8];
#pragma unroll
    for (int s = 0; s < 8; ++s) { b0[s] = 0xFFFFFFFFu; b1[s] = 0xFFFFFFFFu; }

    for (int g = 0; g < 16; ++g) {
        const char* bgp = Bb + (size_t)g * 32768 + voff;
        union { uint4 u; bf16x8 b; } ld[8];
#pragma unroll
        for (int ks = 0; ks < 8; ++ks)
            ld[ks].u = *reinterpret_cast<const uint4*>(bgp + ks * 4096);

        const float efb = Ef[g * 64 + rB] + 0.5f;

        f32x4 acc[2];
#pragma unroll
        for (int mi = 0; mi < 2; ++mi) acc[mi] = f32x4{0.f, 0.f, 0.f, 0.f};
#pragma unroll
        for (int ks = 0; ks < 8; ++ks)
#pragma unroll
            for (int mi = 0; mi < 2; ++mi)
                acc[mi] = __builtin_amdgcn_mfma_f32_16x16x32_bf16(
                    af[mi][ks], ld[ks].b, acc[mi], 0, 0, 0);

        const uint32_t code = (uint32_t)(g * 64 + rB);
#pragma unroll
        for (int mi = 0; mi < 2; ++mi)
#pragma unroll
            for (int rr = 0; rr < 4; ++rr) {
                const float sp = __fmaf_rn(acc[mi][rr], -2.0f, efb);
                const uint32_t key = (__float_as_uint(sp) & 0xFFFFFC00u) | code;
                const int slot = mi * 4 + rr;
                const uint32_t lo = umin32(b0[slot], key);
                const uint32_t hi = umax32(b0[slot], key);
                b0[slot] = lo;
                b1[slot] = umin32(b1[slot], hi);
            }
    }

#pragma unroll
    for (int m = 1; m <= 8; m <<= 1) {
#pragma unroll
        for (int s = 0; s < 8; ++s) {
            const uint32_t o0 = (uint32_t)__shfl_xor((int)b0[s], m);
            const uint32_t o1 = (uint32_t)__shfl_xor((int)b1[s], m);
            const uint32_t lo = umin32(b0[s], o0);
            const uint32_t hi = umax32(b0[s], o0);
            b0[s] = lo;
            b1[s] = umin32(umin32(b1[s], o1), hi);
        }
    }

    __syncthreads();
    uint32_t* ml = reinterpret_cast<uint32_t*>(As);   // [64 rows][4 wN][2]
    if (l15 == 0) {
#pragma unroll
        for (int s = 0; s < 8; ++s) {
            const int row = wM * 32 + (s >> 2) * 16 + kg * 4 + (s & 3);
            ml[(row * 4 + wN) * 2]     = b0[s];
            ml[(row * 4 + wN) * 2 + 1] = b1[s];
        }
    }
    __syncthreads();

    if (t < 64) {
        uint32_t k0 = 0xFFFFFFFFu, k1 = 0xFFFFFFFFu;
#pragma unroll
        for (int w = 0; w < 4; ++w) {
            const uint32_t a0 = ml[(t * 4 + w) * 2];
            const uint32_t a1 = ml[(t * 4 + w) * 2 + 1];
            const uint32_t lo = umin32(k0, a0);
            const uint32_t hi = umax32(k0, a0);
            k0 = lo;
            k1 = umin32(umin32(k1, a1), hi);
        }
        const int n = bidx * 64 + t;
        idxf[n] = (int)(k0 & 1023u);
        const float s0f = __uint_as_float(k0 & 0xFFFFFC00u);
        const float s1f = __uint_as_float(k1 & 0xFFFFFC00u);
        if (s1f - s0f < TAU2) {
            const int p = atomicAdd(count, 1);
            list[p] = n;
        }
    }
}

// ---------------------------------------------------------------------------
// kzn: fused kz_gather + kn_norm. Per 8-row group: gather z rows into padded
// LDS (one scattered pass), write zc coalesced, compute the 8 faithful
// norms in lanes 0-7 (groups spread across blocks -> parallel).
// Numerics identical to validated kz/kn.
// ---------------------------------------------------------------------------
#define RBZ 8
__global__ __launch_bounds__(256) void kzn(const float* __restrict__ z,
                                           const int* __restrict__ list,
                                           const int* __restrict__ count,
                                           float* __restrict__ zc,
                                           float* __restrict__ zn,
                                           int cap) {
    __shared__ float zs[C_DIM][RBZ + 1];   // pad 9: conflict-free col access
    __shared__ int rowsh[RBZ];
    const int t = threadIdx.x;
    const int cnt = min(*count, cap);

    for (int g0 = blockIdx.x * RBZ; g0 < cnt; g0 += gridDim.x * RBZ) {
        const int nrows = min(RBZ, cnt - g0);
        if (t < RBZ) rowsh[t] = list[g0 + min(t, nrows - 1)];
        __syncthreads();
        {
            const int r = t & 7, cg = t >> 3;
            const int row = rowsh[r];
            const int b = row >> 10, hw = row & 1023;
            const float* zp = z + ((size_t)b * C_DIM + cg * 8) * HW + hw;
#pragma unroll
            for (int i = 0; i < 8; ++i)
                zs[cg * 8 + i][r] = zp[(size_t)i * HW];
        }
        __syncthreads();
        // coalesced zc writes
        for (int r = 0; r < nrows; ++r)
            zc[(size_t)(g0 + r) * C_DIM + t] = zs[t][r];
        // faithful numpy-pairwise norms, lanes 0..7
        if (t < nrows) {
            float blk[2];
#pragma unroll
            for (int h = 0; h < 2; ++h) {
                float rr[8];
#pragma unroll
                for (int j = 0; j < 8; ++j) {
                    const float v = zs[h * 128 + j][t];
                    rr[j] = __fmul_rn(v, v);
                }
                for (int i = 8; i < 128; i += 8) {
#pragma unroll
                    for (int j = 0; j < 8; ++j) {
                        const float v = zs[h * 128 + i + j][t];
                        rr[j] = __fadd_rn(rr[j], __fmul_rn(v, v));
                    }
                }
                blk[h] = __fadd_rn(__fadd_rn(__fadd_rn(rr[0], rr[1]), __fadd_rn(rr[2], rr[3])),
                                   __fadd_rn(__fadd_rn(rr[4], rr[5]), __fadd_rn(rr[6], rr[7])));
            }
            zn[g0 + t] = __fadd_rn(blk[0], blk[1]);
        }
        __syncthreads();
    }
}

// ---------------------------------------------------------------------------
// k3 v7: code-quarter-split faithful fp32 re-score (validated r12-18).
// ---------------------------------------------------------------------------
#define RB3 8
__global__ __launch_bounds__(256, 4) void k3_refine(const float* __restrict__ z,
                                                    const float* __restrict__ zc,
                                                    const float* __restrict__ zn,
                                                    const float* __restrict__ embT,
                                                    const float* __restrict__ Ef,
                                                    const int* __restrict__ list,
                                                    const int* __restrict__ count,
                                                    unsigned long long* __restrict__ slots,
                                                    int cap) {
    __shared__ __align__(16) float zs[C_DIM][RB3];   // 8 KB, [c][row]
    __shared__ int   rowsh[RB3];
    __shared__ float znsh[RB3];
    __shared__ unsigned long long wk[4][RB3];

    const int t = threadIdx.x;
    const int lane = t & 63, w = t >> 6;
    const int cnt = *count;
    const int ngroups = (cnt + RB3 - 1) / RB3;
    const int q = blockIdx.x & 3;
    const int code = q * 256 + t;

    for (int gi = blockIdx.x >> 2; gi < ngroups; gi += (gridDim.x >> 2)) {
        const int g0 = gi * RB3;
        const int nrows = min(RB3, cnt - g0);
        if (t < RB3) rowsh[t] = list[g0 + min(t, nrows - 1)];
        __syncthreads();

        {   // z rows -> zs[c][r]: compact path (L2) or strided fallback
            const int r = t & 7, cg = t >> 3;
            const int li = g0 + min(r, nrows - 1);
            if (li < cap) {
                const float* zp = zc + (size_t)li * C_DIM + cg * 8;
#pragma unroll
                for (int i = 0; i < 8; ++i)
                    zs[cg * 8 + i][r] = zp[i];
            } else {
                const int row = rowsh[r];
                const int b = row >> 10, hw = row & 1023;
                const float* zp = z + ((size_t)b * C_DIM + cg * 8) * HW + hw;
#pragma unroll
                for (int i = 0; i < 8; ++i)
                    zs[cg * 8 + i][r] = zp[(size_t)i * HW];
            }
        }
        __syncthreads();

        if (t < RB3) {
            const int li = g0 + min(t, nrows - 1);
            if (li < cap) {
                znsh[t] = zn[li];            // precomputed by kzn
            } else {                          // fallback: serial faithful compute
                float blk[2];
#pragma unroll
                for (int h = 0; h < 2; ++h) {
                    float rr[8];
#pragma unroll
                    for (int j = 0; j < 8; ++j) {
                        const float v = zs[h * 128 + j][t];
                        rr[j] = __fmul_rn(v, v);
                    }
                    for (int i = 8; i < 128; i += 8) {
#pragma unroll
                        for (int j = 0; j < 8; ++j) {
                            const float v = zs[h * 128 + i + j][t];
                            rr[j] = __fadd_rn(rr[j], __fmul_rn(v, v));
                        }
                    }
                    blk[h] = __fadd_rn(__fadd_rn(__fadd_rn(rr[0], rr[1]), __fadd_rn(rr[2], rr[3])),
                                       __fadd_rn(__fadd_rn(rr[4], rr[5]), __fadd_rn(rr[6], rr[7])));
                }
                znsh[t] = __fadd_rn(blk[0], blk[1]);
            }
        }
        __syncthreads();

        float acc[RB3];
#pragma unroll
        for (int r = 0; r < RB3; ++r) acc[r] = 0.f;

        const float* ebase = embT + code;
#pragma unroll 8
        for (int c = 0; c < C_DIM; ++c) {
            const float ev = ebase[(size_t)c * K_CODES];
            float zv[RB3];
            *reinterpret_cast<float4*>(&zv[0]) = *reinterpret_cast<const float4*>(&zs[c][0]);
            *reinterpret_cast<float4*>(&zv[4]) = *reinterpret_cast<const float4*>(&zs[c][4]);
#pragma unroll
            for (int r = 0; r < RB3; ++r)
                acc[r] = __fmaf_rn(zv[r], ev, acc[r]);
        }

        const float ef = Ef[code];
        unsigned long long key[RB3];
#pragma unroll
        for (int r = 0; r < RB3; ++r) {
            const float dk = __fsub_rn(__fadd_rn(znsh[r], ef), __fmul_rn(2.0f, acc[r]));
            key[r] = ((unsigned long long)__float_as_uint(dk) << 32) | (unsigned int)code;
        }
#pragma unroll
        for (int m = 1; m <= 32; m <<= 1) {
#pragma unroll
            for (int r = 0; r < RB3; ++r) {
                const unsigned long long o = __shfl_xor(key[r], m);
                if (o < key[r]) key[r] = o;
            }
        }
        if (lane == 0) {
#pragma unroll
            for (int r = 0; r < RB3; ++r) wk[w][r] = key[r];
        }
        __syncthreads();
        if (t < RB3) {
            unsigned long long kk = wk[0][t];
#pragma unroll
            for (int ww = 1; ww < 4; ++ww)
                if (wk[ww][t] < kk) kk = wk[ww][t];
            if (t < nrows) atomicMin(&slots[rowsh[t]], kk);
        }
        __syncthreads();
    }
}

// ---------------------------------------------------------------------------
// k3b: write final indices for flagged rows from the u64 slots.
// ---------------------------------------------------------------------------
__global__ __launch_bounds__(256) void k3b_write(const int* __restrict__ list,
                                                 const int* __restrict__ count,
                                                 const unsigned long long* __restrict__ slots,
                                                 int* __restrict__ idxf) {
    const int cnt = *count;
    for (int i = blockIdx.x * 256 + threadIdx.x; i < cnt; i += gridDim.x * 256)
        idxf[list[i]] = (int)(slots[list[i]] & 1023ull);
}

// ---------------------------------------------------------------------------
// k4 v3: (c, b-quad) slab writer (validated rounds 15-18).
// ---------------------------------------------------------------------------
__global__ __launch_bounds__(256) void k4_out(const float* __restrict__ z,
                                              const float* __restrict__ embT,
                                              const int* __restrict__ idxf,
                                              float* __restrict__ out,
                                              double* __restrict__ pd) {
    const int t = threadIdx.x;
    const int c = blockIdx.x & 255, bq = blockIdx.x >> 8;   // bq in [0,8)
    const float* er = embT + (size_t)c * K_CODES;

    double acc = 0.0;
#pragma unroll
    for (int i = 0; i < 4; ++i) {
        const int b = bq * 4 + i;
        const size_t base = ((size_t)b * C_DIM + c) * HW + t * 4;
        const float4 zv = *reinterpret_cast<const float4*>(z + base);
        const int4  jv = *reinterpret_cast<const int4*>(idxf + b * HW + t * 4);
        const float e0 = er[jv.x], e1 = er[jv.y], e2 = er[jv.z], e3 = er[jv.w];

        float4 o;
        o.x = zv.x + (e0 - zv.x);
        o.y = zv.y + (e1 - zv.y);
        o.z = zv.z + (e2 - zv.z);
        o.w = zv.w + (e3 - zv.w);
        *reinterpret_cast<float4*>(out + base) = o;

        if (c == 0) {
            float4 fi;
            fi.x = (float)jv.x; fi.y = (float)jv.y; fi.z = (float)jv.z; fi.w = (float)jv.w;
            *reinterpret_cast<float4*>(out + (size_t)ZQ_ELEMS + 3 + b * HW + t * 4) = fi;
        }

        const double d0 = (double)e0 - (double)zv.x;
        const double d1 = (double)e1 - (double)zv.y;
        const double d2 = (double)e2 - (double)zv.z;
        const double d3 = (double)e3 - (double)zv.w;
        acc += d0 * d0 + d1 * d1 + d2 * d2 + d3 * d3;
    }

#pragma unroll
    for (int off = 32; off > 0; off >>= 1) acc += __shfl_down(acc, off);
    __shared__ double wsum[4];
    const int w = t >> 6, lanei = t & 63;
    if (lanei == 0) wsum[w] = acc;
    __syncthreads();
    if (t == 0) pd[blockIdx.x] = wsum[0] + wsum[1] + wsum[2] + wsum[3];
}

// ---------------------------------------------------------------------------
// k5: reduce the 2048 per-block partials (deterministic) + emit losses.
// ---------------------------------------------------------------------------
__global__ __launch_bounds__(256) void k5_loss(const double* __restrict__ pd,
                                               float* __restrict__ out) {
    const int t = threadIdx.x;
    double a = 0.0;
    for (int i = t; i < 2048; i += 256) a += pd[i];
#pragma unroll
    for (int off = 32; off > 0; off >>= 1) a += __shfl_down(a, off);
    __shared__ double wsum[4];
    const int w = t >> 6, lanei = t & 63;
    if (lanei == 0) wsum[w] = a;
    __syncthreads();
    if (t == 0) {
        const double m = (wsum[0] + wsum[1] + wsum[2] + wsum[3]) / (double)ZQ_ELEMS;
        const float cm = (float)(0.25 * m);
        const float cb = (float)m;
        out[ZQ_ELEMS]     = cm + cb;
        out[ZQ_ELEMS + 1] = cm;
        out[ZQ_ELEMS + 2] = cb;
    }
}

extern "C" void kernel_launch(void* const* d_in, const int* in_sizes, int n_in,
                              void* d_out, int out_size, void* d_ws, size_t ws_size,
                              hipStream_t stream) {
    const float* z   = (const float*)d_in[0];
    const float* emb = (const float*)d_in[1];
    float* out = (float*)d_out;
    char* ws = (char*)d_ws;

    float*  Ef    = (float*)(ws + OFF_EF);
    char*   Bb    = ws + OFF_BB;
    int*    idxf  = (int*)(ws + OFF_IDX);
    int*    list  = (int*)(ws + OFF_LIST);
    int*    count = (int*)(ws + OFF_COUNT);
    double* lsum  = (double*)(ws + OFF_LSUM);
    float*  embT  = (float*)(ws + OFF_ET);
    unsigned long long* slots = (unsigned long long*)(ws + OFF_SLOT);
    double* pd    = (double*)(ws + OFF_PD);
    float*  zn    = (float*)(ws + OFF_ZN);
    float*  zc    = (float*)(ws + OFF_ZC);

    int cap = 0;
    if (ws_size > (size_t)OFF_ZC + 1024)
        cap = (int)((ws_size - (size_t)OFF_ZC) / 1024);
    if (cap > NPOS) cap = NPOS;

    kprep<<<64, 256, 0, stream>>>(emb, Ef, Bb, count, lsum, embT, slots);
    k2_gemm<<<512, 512, 0, stream>>>(z, Bb, Ef, idxf, list, count);
    kzn<<<512, 256, 0, stream>>>(z, list, count, zc, zn, cap);
    k3_refine<<<4096, 256, 0, stream>>>(z, zc, zn, embT, Ef, list, count, slots, cap);
    k3b_write<<<64, 256, 0, stream>>>(list, count, slots, idxf);
    k4_out<<<2048, 256, 0, stream>>>(z, embT, idxf, out, pd);
    k5_loss<<<1, 256, 0, stream>>>(pd, out);
}